// Round 6
// baseline (3244.012 us; speedup 1.0000x reference)
//
#include <hip/hip_runtime.h>
#include <hip/hip_bf16.h>

#define Hh 1024
#define INs 512
#define Bb 256
#define Tt 256
#define DT_ 0.1f
#define Z_MIN_ 0.001f
#define Z_MAX_ 0.1f
#define KW (Hh + INs)   // 1536 combined K
#define NB 256          // persistent grid = 1 block per CU

typedef __attribute__((ext_vector_type(8))) short short8;
typedef __attribute__((ext_vector_type(4))) float f32x4;

__device__ __forceinline__ float sigmoidf_(float x) {
    return 1.0f / (1.0f + __expf(-x));
}

__device__ __forceinline__ unsigned short f2bf(float f) {
    union { float f; unsigned u; } v; v.f = f;
    unsigned r = v.u + 0x7FFFu + ((v.u >> 16) & 1u);  // RNE
    return (unsigned short)(r >> 16);
}

// ---- build W1=[K|p_z], W2=[w_r|p_r] as bf16 row-major 1024 x 1536 ----
__global__ __launch_bounds__(256) void build_weights(
    const float* __restrict__ Km, const float* __restrict__ p_z,
    const float* __restrict__ w_r, const float* __restrict__ p_r,
    unsigned short* __restrict__ W1, unsigned short* __restrict__ W2) {
    int idx = blockIdx.x * 256 + threadIdx.x;
    int h = idx / KW, k = idx % KW;
    float a = (k < Hh) ? Km[h * Hh + k] : p_z[h * INs + (k - Hh)];
    float b = (k < Hh) ? w_r[h * Hh + k] : p_r[h * INs + (k - Hh)];
    W1[idx] = f2bf(a);
    W2[idx] = f2bf(b);
}

// ---- x (T, IN, B) fp32 -> xT (T, B, IN) bf16 ----
__global__ __launch_bounds__(256) void transpose_x(
    const float* __restrict__ x, unsigned short* __restrict__ xT) {
    __shared__ unsigned short tile[64][65];
    int t = blockIdx.z;
    int i0 = blockIdx.y * 64;
    int b0 = blockIdx.x * 64;
    int c = threadIdx.x & 63, rbase = threadIdx.x >> 6;
    const float* xp = x + (size_t)t * INs * Bb;
#pragma unroll
    for (int r = 0; r < 16; ++r) {
        int row = r * 4 + rbase;
        tile[row][c] = f2bf(xp[(size_t)(i0 + row) * Bb + (b0 + c)]);
    }
    __syncthreads();
    unsigned short* op = xT + (size_t)t * Bb * INs;
#pragma unroll
    for (int r = 0; r < 16; ++r) {
        int brow = r * 4 + rbase;
        op[(size_t)(b0 + brow) * INs + (i0 + c)] = tile[c][brow];
    }
}

// ---- gate-rate constants (H each) ----
__global__ __launch_bounds__(256) void precomp_gates(
    const float* __restrict__ c_x, const float* __restrict__ c_u,
    const float* __restrict__ c_U,
    float* __restrict__ zxv, float* __restrict__ zuv, float* __restrict__ Ucv) {
    int h = blockIdx.x * 256 + threadIdx.x;
    zxv[h] = Z_MIN_ + (Z_MAX_ - Z_MIN_) * sigmoidf_(c_x[h]);
    zuv[h] = Z_MIN_ + (Z_MAX_ - Z_MIN_) * sigmoidf_(c_u[h]);
    Ucv[h] = 0.9f * sigmoidf_(c_U[h]);
}

// ---- initial R_0, M_0 (B,H) bf16 ; zero the barrier flag region (2KB) ----
__global__ __launch_bounds__(256) void init_state(
    const float* __restrict__ zxv, const float* __restrict__ zuv,
    const float* __restrict__ Ucv,
    unsigned short* __restrict__ R0, unsigned short* __restrict__ M0,
    unsigned* __restrict__ bar) {
    int idx = blockIdx.x * 256 + threadIdx.x;           // over B*H
    if (idx < 512) bar[idx] = 0;                        // 16 groups x 128B
    int h = idx & (Hh - 1);
    float zx = zxv[h], zu = zuv[h], Uc = Ucv[h];
    const float r = 0.5f;                                // sigmoid(0)
    float Xn = zx + (1.0f - zx) - 0.45f;                 // X0=1,U0=0.9
    float Un = Uc * zu + (1.0f - zu) * 0.9f + Uc * 0.05f;
    Un = fminf(fmaxf(Un, Uc), 1.0f);
    R0[idx] = f2bf(r);
    M0[idx] = f2bf(Un * Xn * r);
}

// ---- persistent kernel: all 256 timesteps ----
// R6 = R5 resubmit with the poll de-risked (R5 bench died in infra with no
// verdict, same signature as R2 whose identical resubmit passed). The only
// exotic R5 construct — inline-asm global_load_dwordx4 poll — is replaced by
// compiler-generated relaxed agent-scope atomic loads (correct L1-bypassing
// cache bits guaranteed by the compiler).
//
// R5 design (unchanged):
//  (1) epilogue: 4 waves x 4 outs/lane -> f32x4/ushort4 coalesced full-line
//      stores (fixes R4's WRITE_SIZE 266->468MB partial-line split) and
//      conflict-free b128 LDS reduction reads (fixes R4's 3.4e7 conflicts).
//  (2) byte-flag barrier: each block byte-stores arrival value t+1 into its
//      own byte of its colg group's 16B line (disjoint bytes, no RMW chain);
//      poller reads all 16 flags with two 8B relaxed agent atomic loads and
//      tests "all bytes >= t+1" via SWAR has-zero on flags ^ broadcast(t)
//      (flag values are provably in {t, t+1, t+2}; max 255, no wrap).
//  (3) per-step issue order: state loads FIRST (vmcnt FIFO is in-order),
//      then register-only xproj MFMAs overlap their latency, then xb(t+1)
//      prefetch (younger than state loads), then recurrent MFMAs.
//
// SYNC invariant (verified R1/R3/R4): state exchange is intra-XCD
// (blockIdx%16==colg -> %8 same XCD); stores drain to the shared L2 at the
// pre-barrier vmcnt(0) of __syncthreads(); per-CU L1-only invalidate
// (buffer_inv sc0) after the wait. No agent-scope L2 walks.
__global__ __launch_bounds__(512, 1) void persist_kernel(
    const unsigned short* __restrict__ W1, const unsigned short* __restrict__ W2,
    const unsigned short* __restrict__ xT,
    unsigned short* __restrict__ Rb0, unsigned short* __restrict__ Rb1,
    unsigned short* __restrict__ Mb0, unsigned short* __restrict__ Mb1,
    float* __restrict__ out,
    const float* __restrict__ g_z, const float* __restrict__ b_r,
    const float* __restrict__ zxv, const float* __restrict__ zuv,
    const float* __restrict__ Ucv, unsigned* __restrict__ bar) {

    const int tid = threadIdx.x;
    const int wave = tid >> 6, lane = tid & 63;
    const int m = lane & 15, q = lane >> 4;
    const int kq = wave;               // 0..7: K eighth
    const int rowg = blockIdx.x >> 4;  // 16 row groups (64 rows each)
    const int colg = blockIdx.x & 15;  // 16 col groups (16 cols) — XCD-aligned

    unsigned char* flg = (unsigned char*)bar + (unsigned)colg * 128;

    const int krec = kq * 128;                 // recurrent K base (eighth)
    const int kx = kq * 64;                    // x-proj K base (eighth of IN)
    const int bcol = colg * 16 + m;

    // ---- pin weights: 4 rowsets x (4 rec + 2 x) chunks x 2 matrices ----
    short8 wf1[4][6], wf2[4][6];
#pragma unroll
    for (int rs = 0; rs < 4; ++rs) {
        const int arow = rowg * 64 + rs * 16 + m;
        const unsigned short* w1r = W1 + (size_t)arow * KW + krec + q * 8;
        const unsigned short* w2r = W2 + (size_t)arow * KW + krec + q * 8;
#pragma unroll
        for (int c = 0; c < 4; ++c) {
            wf1[rs][c] = *(const short8*)(w1r + c * 32);
            wf2[rs][c] = *(const short8*)(w2r + c * 32);
        }
        const unsigned short* w1x = W1 + (size_t)arow * KW + Hh + kx + q * 8;
        const unsigned short* w2x = W2 + (size_t)arow * KW + Hh + kx + q * 8;
#pragma unroll
        for (int c = 0; c < 2; ++c) {
            wf1[rs][4 + c] = *(const short8*)(w1x + c * 32);
            wf2[rs][4 + c] = *(const short8*)(w2x + c * 32);
        }
    }

    // ---- epilogue: waves 0..3 each own rowset rs_e=wave, 4 outs/lane ----
    const int rs_e = wave & 3;
    const int h04 = rowg * 64 + rs_e * 16 + q * 4;
    const int bcol_e = colg * 16 + m;

    f32x4 zx4 = *(const f32x4*)(zxv + h04);
    f32x4 zu4 = *(const f32x4*)(zuv + h04);
    f32x4 Uc4 = *(const f32x4*)(Ucv + h04);
    f32x4 gz4 = *(const f32x4*)(g_z + h04);
    f32x4 br4 = *(const f32x4*)(b_r + h04);

    f32x4 vr, Xr, Ur;
#pragma unroll
    for (int e = 0; e < 4; ++e) {
        vr[e] = 0.0f;
        float Xn = zx4[e] + (1.0f - zx4[e]) - 0.45f;
        float Un = Uc4[e] * zu4[e] + (1.0f - zu4[e]) * 0.9f + Uc4[e] * 0.05f;
        Un = fminf(fmaxf(Un, Uc4[e]), 1.0f);
        Xr[e] = Xn; Ur[e] = Un;
    }

    __shared__ f32x4 red[8][4][2][64];   // [kq][rs][mat][lane] = 64 KB

    // ---- prologue: prefetch x-operands for t=0 into registers ----
    short8 xb[2];
    {
        const unsigned short* xp = xT + (size_t)bcol * INs + kx + q * 8;
#pragma unroll
        for (int c = 0; c < 2; ++c)
            xb[c] = *(const short8*)(xp + c * 32);
    }

    for (int t = 0; t < Tt; ++t) {
        const unsigned short* Rt = (t & 1) ? Rb1 : Rb0;
        const unsigned short* Mt = (t & 1) ? Mb1 : Mb0;
        unsigned short* Rn = (t & 1) ? Rb0 : Rb1;
        unsigned short* Mn = (t & 1) ? Mb0 : Mb1;

        // ---- 1) issue state loads FIRST (critical path after barrier) ----
        const unsigned short* rp = Rt + (size_t)bcol * Hh + krec + q * 8;
        const unsigned short* mp = Mt + (size_t)bcol * Hh + krec + q * 8;
        short8 bR[4], bM[4];
#pragma unroll
        for (int c = 0; c < 4; ++c) {
            bR[c] = *(const short8*)(rp + c * 32);
            bM[c] = *(const short8*)(mp + c * 32);
        }

        // acc[rowset][mat]
        f32x4 acc[4][2];
#pragma unroll
        for (int rs = 0; rs < 4; ++rs)
#pragma unroll
            for (int mt = 0; mt < 2; ++mt)
                acc[rs][mt] = (f32x4){0.0f, 0.0f, 0.0f, 0.0f};

        // ---- 2) x-projection: register-only MFMAs — overlap load latency --
#pragma unroll
        for (int c = 0; c < 2; ++c)
#pragma unroll
            for (int rs = 0; rs < 4; ++rs) {
                acc[rs][0] = __builtin_amdgcn_mfma_f32_16x16x32_bf16(wf1[rs][4 + c], xb[c], acc[rs][0], 0, 0, 0);
                acc[rs][1] = __builtin_amdgcn_mfma_f32_16x16x32_bf16(wf2[rs][4 + c], xb[c], acc[rs][1], 0, 0, 0);
            }

        // ---- 3) prefetch x-operands for t+1 (younger than state loads —
        //      vmcnt FIFO: state-operand waits don't drain this) ----
        if (t + 1 < Tt) {
            const unsigned short* xn = xT + (size_t)(t + 1) * Bb * INs
                                     + (size_t)bcol * INs + kx + q * 8;
#pragma unroll
            for (int c = 0; c < 2; ++c)
                xb[c] = *(const short8*)(xn + c * 32);
        }

        // ---- 4) recurrent eighth: disjoint per-wave B streams ----
#pragma unroll
        for (int c = 0; c < 4; ++c)
#pragma unroll
            for (int rs = 0; rs < 4; ++rs) {
                acc[rs][0] = __builtin_amdgcn_mfma_f32_16x16x32_bf16(wf1[rs][c], bR[c], acc[rs][0], 0, 0, 0);
                acc[rs][1] = __builtin_amdgcn_mfma_f32_16x16x32_bf16(wf2[rs][c], bM[c], acc[rs][1], 0, 0, 0);
            }

        // ---- cross-wave K reduction in LDS (contiguous b128, no conflict) --
#pragma unroll
        for (int rs = 0; rs < 4; ++rs)
#pragma unroll
            for (int mt = 0; mt < 2; ++mt)
                red[kq][rs][mt][lane] = acc[rs][mt];
        __syncthreads();

        // ---- epilogue: waves 0..3, one rowset each, 4 outs/lane ----
        if (wave < 4) {
            f32x4 g1 = red[0][rs_e][0][lane];
            f32x4 g2 = red[0][rs_e][1][lane];
#pragma unroll
            for (int k2 = 1; k2 < 8; ++k2) {
                g1 += red[k2][rs_e][0][lane];
                g2 += red[k2][rs_e][1][lane];
            }

            f32x4 vv;
            ushort4 rq, mq;
#pragma unroll
            for (int e = 0; e < 4; ++e) {
                float z = DT_ * sigmoidf_(g1[e] + gz4[e]);
                float vnew = (1.0f - z) * vr[e] + DT_ * (g2[e] + br4[e]);
                vr[e] = vnew;
                vv[e] = vnew;
                float r = sigmoidf_(vnew);
                float Xs = Xr[e], Us = Ur[e];
                float Xn = zx4[e] + (1.0f - zx4[e]) * Xs - Us * Xs * r;
                float Un = Uc4[e] * zu4[e] + (1.0f - zu4[e]) * Us
                         + Uc4[e] * (1.0f - Us) * r;
                Un = fminf(fmaxf(Un, Uc4[e]), 1.0f);
                Xr[e] = Xn; Ur[e] = Un;
                unsigned short rb = f2bf(r), mb = f2bf(Un * Xn * r);
                if (e == 0) { rq.x = rb; mq.x = mb; }
                else if (e == 1) { rq.y = rb; mq.y = mb; }
                else if (e == 2) { rq.z = rb; mq.z = mb; }
                else { rq.w = rb; mq.w = mb; }
            }
            const size_t base = (size_t)bcol_e * Hh + h04;
            *(f32x4*)(out + (size_t)t * Bb * Hh + base) = vv;
            *(ushort4*)(Rn + base) = rq;
            *(ushort4*)(Mn + base) = mq;
        }
        __syncthreads();   // per-wave vmcnt(0) drain -> all state stores of
                           // this block visible in this XCD's L2

        if (t + 1 < Tt) {
            if (tid == 0) {
                // ---- arrive: own byte, no RMW, pipelined across blocks ----
                __hip_atomic_store(flg + rowg, (unsigned char)(t + 1),
                                   __ATOMIC_RELAXED, __HIP_MEMORY_SCOPE_AGENT);
                // ---- wait: two 8B relaxed agent atomic loads cover all 16
                //      peer flags; "all >= t+1" == "no byte == t" (values
                //      are provably in {t, t+1, t+2}; no wrap, max 255) ----
                const unsigned long long* f64 =
                    (const unsigned long long*)flg;
                const unsigned long long low = 0x0101010101010101ull;
                const unsigned long long hib = 0x8080808080808080ull;
                const unsigned long long pat = low * (unsigned char)t;
                for (;;) {
                    unsigned long long a = __hip_atomic_load(
                        f64, __ATOMIC_RELAXED, __HIP_MEMORY_SCOPE_AGENT);
                    unsigned long long b = __hip_atomic_load(
                        f64 + 1, __ATOMIC_RELAXED, __HIP_MEMORY_SCOPE_AGENT);
                    unsigned long long xa = a ^ pat, xb2 = b ^ pat;
                    unsigned long long za = (xa - low) & ~xa & hib;
                    unsigned long long zb = (xb2 - low) & ~xb2 & hib;
                    if ((za | zb) == 0ull) break;
                    __builtin_amdgcn_s_sleep(1);
                }
                // L1-only flash invalidate: peers' fresh R/M is in our shared
                // L2; drop stale per-CU L1 lines. NOT a full-L2 walk.
                asm volatile("buffer_inv sc0" ::: "memory");
            }
            __syncthreads();
        }
    }
}

extern "C" void kernel_launch(void* const* d_in, const int* in_sizes, int n_in,
                              void* d_out, int out_size, void* d_ws, size_t ws_size,
                              hipStream_t stream) {
    const float* x   = (const float*)d_in[0];
    const float* c_x = (const float*)d_in[1];
    const float* c_u = (const float*)d_in[2];
    const float* c_U = (const float*)d_in[3];
    const float* w_r = (const float*)d_in[4];
    const float* p_r = (const float*)d_in[5];
    const float* b_r = (const float*)d_in[6];
    const float* g_z = (const float*)d_in[7];
    const float* Km  = (const float*)d_in[8];
    const float* p_z = (const float*)d_in[9];
    float* out = (float*)d_out;

    char* w = (char*)d_ws;
    unsigned short* W1 = (unsigned short*)w;   w += (size_t)Hh * KW * 2;
    unsigned short* W2 = (unsigned short*)w;   w += (size_t)Hh * KW * 2;
    unsigned short* xT = (unsigned short*)w;   w += (size_t)Tt * Bb * INs * 2;
    unsigned short* Rb0 = (unsigned short*)w;  w += (size_t)Bb * Hh * 2;
    unsigned short* Rb1 = (unsigned short*)w;  w += (size_t)Bb * Hh * 2;
    unsigned short* Mb0 = (unsigned short*)w;  w += (size_t)Bb * Hh * 2;
    unsigned short* Mb1 = (unsigned short*)w;  w += (size_t)Bb * Hh * 2;
    float* zxv = (float*)w;                    w += 4096;
    float* zuv = (float*)w;                    w += 4096;
    float* Ucv = (float*)w;                    w += 4096;
    unsigned* bar = (unsigned*)w;              w += 4096;

    build_weights<<<(Hh * KW) / 256, 256, 0, stream>>>(Km, p_z, w_r, p_r, W1, W2);
    transpose_x<<<dim3(Bb / 64, INs / 64, Tt), 256, 0, stream>>>(x, xT);
    precomp_gates<<<Hh / 256, 256, 0, stream>>>(c_x, c_u, c_U, zxv, zuv, Ucv);
    init_state<<<(Bb * Hh) / 256, 256, 0, stream>>>(zxv, zuv, Ucv, Rb0, Mb0, bar);

    persist_kernel<<<NB, 512, 0, stream>>>(
        W1, W2, xT, Rb0, Rb1, Mb0, Mb1, out,
        g_z, b_r, zxv, zuv, Ucv, bar);
}